// Round 1
// baseline (61.515 us; speedup 1.0000x reference)
//
#include <hip/hip_runtime.h>
#include <math.h>

#define DIM 128
#define PSTRIDE (DIM + 2)   // per-partial floats: m, l, acc[128]

// ---------------------------------------------------------------------------
// Pass 1: each wave owns a strided set of rows. For each row:
//   logit = -sum_d |keys[row][d] - query[d]|   (wave shfl-xor reduce)
//   online-softmax accumulate of values[row] into per-wave (m, l, acc[128]).
// Lane i holds elements [2i, 2i+1] of query / key-row / value-row / acc.
// Writes one partial (m, l, acc[128]) per wave to ws.
// ---------------------------------------------------------------------------
__global__ __launch_bounds__(256) void nd_pass1(const float* __restrict__ query,
                                                const float* __restrict__ keys,
                                                const float* __restrict__ values,
                                                float* __restrict__ ws,
                                                int nrows, int P) {
    const int tid  = threadIdx.x;
    const int lane = tid & 63;
    const int wib  = tid >> 6;                       // wave in block
    const int p    = blockIdx.x * (blockDim.x >> 6) + wib;

    const float2 q = *reinterpret_cast<const float2*>(query + lane * 2);

    float  m = -INFINITY;
    float  l = 0.f;
    float2 acc = make_float2(0.f, 0.f);

    for (int row = p; row < nrows; row += P) {
        const float2 kv = *reinterpret_cast<const float2*>(keys + (size_t)row * DIM + lane * 2);
        float s = fabsf(kv.x - q.x) + fabsf(kv.y - q.y);
        #pragma unroll
        for (int off = 32; off > 0; off >>= 1)
            s += __shfl_xor(s, off, 64);
        const float logit = -s;                       // same value in all 64 lanes

        const float newm  = fmaxf(m, logit);
        const float scale = __expf(m - newm);         // 0 on first iter (m=-inf)
        const float w     = __expf(logit - newm);

        const float2 vv = *reinterpret_cast<const float2*>(values + (size_t)row * DIM + lane * 2);
        acc.x = acc.x * scale + w * vv.x;
        acc.y = acc.y * scale + w * vv.y;
        l     = l * scale + w;
        m     = newm;
    }

    float* wp = ws + (size_t)p * PSTRIDE;
    if (lane == 0) { wp[0] = m; wp[1] = l; }
    *reinterpret_cast<float2*>(wp + 2 + lane * 2) = acc;
}

// ---------------------------------------------------------------------------
// Pass 2: each block merges 64 consecutive partials into one partial.
// Merge rule (associative): M = max m_p; e_p = exp(m_p - M);
//   l = sum l_p e_p; acc[d] = sum acc_p[d] e_p.
// ---------------------------------------------------------------------------
__global__ __launch_bounds__(256) void nd_pass2(const float* __restrict__ ws,
                                                float* __restrict__ ws2) {
    __shared__ float sh_e[64];
    __shared__ float sh_red[256];
    __shared__ float shM, shL;
    const int tid  = threadIdx.x;
    const int base = blockIdx.x * 64;

    if (tid < 64) {
        const float mm = ws[(size_t)(base + tid) * PSTRIDE];
        float r = mm;
        #pragma unroll
        for (int off = 32; off > 0; off >>= 1)
            r = fmaxf(r, __shfl_xor(r, off, 64));
        const float e = __expf(mm - r);
        sh_e[tid] = e;
        float lp = ws[(size_t)(base + tid) * PSTRIDE + 1] * e;
        #pragma unroll
        for (int off = 32; off > 0; off >>= 1)
            lp += __shfl_xor(lp, off, 64);
        if (tid == 0) { shM = r; shL = lp; }
    }
    __syncthreads();

    const int d = tid & 127, g = tid >> 7;
    float o = 0.f;
    for (int p = g; p < 64; p += 2)
        o += ws[(size_t)(base + p) * PSTRIDE + 2 + d] * sh_e[p];
    sh_red[tid] = o;
    __syncthreads();

    if (tid < 128) {
        float* wp = ws2 + (size_t)blockIdx.x * PSTRIDE;
        if (tid == 0) { wp[0] = shM; wp[1] = shL; }
        wp[2 + tid] = sh_red[tid] + sh_red[tid + 128];
    }
}

// ---------------------------------------------------------------------------
// Pass 3: single block merges the B2 (<=128) level-2 partials and normalizes.
// ---------------------------------------------------------------------------
__global__ __launch_bounds__(256) void nd_pass3(const float* __restrict__ ws2,
                                                float* __restrict__ out, int B2) {
    __shared__ float sh_e[128];
    __shared__ float sh_red[256];
    __shared__ float shL;
    const int tid = threadIdx.x;

    if (tid < 64) {
        const float m0 = (tid      < B2) ? ws2[(size_t)tid * PSTRIDE]        : -INFINITY;
        const float m1 = (tid + 64 < B2) ? ws2[(size_t)(tid + 64) * PSTRIDE] : -INFINITY;
        float r = fmaxf(m0, m1);
        #pragma unroll
        for (int off = 32; off > 0; off >>= 1)
            r = fmaxf(r, __shfl_xor(r, off, 64));
        const float e0 = (tid      < B2) ? __expf(m0 - r) : 0.f;
        const float e1 = (tid + 64 < B2) ? __expf(m1 - r) : 0.f;
        sh_e[tid] = e0; sh_e[tid + 64] = e1;
        float lp = 0.f;
        if (tid      < B2) lp += ws2[(size_t)tid * PSTRIDE + 1] * e0;
        if (tid + 64 < B2) lp += ws2[(size_t)(tid + 64) * PSTRIDE + 1] * e1;
        #pragma unroll
        for (int off = 32; off > 0; off >>= 1)
            lp += __shfl_xor(lp, off, 64);
        if (tid == 0) shL = lp;
    }
    __syncthreads();

    const int d = tid & 127, g = tid >> 7;
    float o = 0.f;
    for (int p = g; p < B2; p += 2)
        o += ws2[(size_t)p * PSTRIDE + 2 + d] * sh_e[p];
    sh_red[tid] = o;
    __syncthreads();

    if (tid < 128)
        out[tid] = (sh_red[tid] + sh_red[tid + 128]) / shL;
}

extern "C" void kernel_launch(void* const* d_in, const int* in_sizes, int n_in,
                              void* d_out, int out_size, void* d_ws, size_t ws_size,
                              hipStream_t stream) {
    const float* query  = (const float*)d_in[0];
    const float* keys   = (const float*)d_in[1];
    const float* values = (const float*)d_in[2];
    float* out = (float*)d_out;
    float* ws  = (float*)d_ws;

    const int nrows = in_sizes[1] / DIM;

    // P1 waves in pass 1; fit (P1 + P1/64) partials of PSTRIDE floats in ws.
    int P1 = 8192;
    const size_t cap = ws_size / (PSTRIDE * sizeof(float));
    while ((size_t)(P1 + P1 / 64) > cap && P1 > 256) P1 >>= 1;

    const int blocks1 = P1 / 4;        // 4 waves (256 threads) per block
    const int B2      = P1 / 64;       // level-2 partial count (<=128)
    float* ws2 = ws + (size_t)P1 * PSTRIDE;

    nd_pass1<<<blocks1, 256, 0, stream>>>(query, keys, values, ws, nrows, P1);
    nd_pass2<<<B2, 256, 0, stream>>>(ws, ws2);
    nd_pass3<<<1, 256, 0, stream>>>(ws2, out, B2);
}